// Round 5
// baseline (176.382 us; speedup 1.0000x reference)
//
#include <hip/hip_runtime.h>
#include <hip/hip_bf16.h>

// DenseGridNet R5: fused-v2.
//  - bf16 emb table in d_ws (8 MB; ~50% L2-resident -> halved texel miss bytes)
//  - fused gather+MLP, launch_bounds(256,4) (16 waves/CU), lean registers
//  - depth-2 pipeline: next tile's 4x8B texel loads + x in flight during MLP
//  - non-temporal x loads / out stores (protect L2 table residency)
//  - b1 folded into w1 row 5 (in8 slot5 = 1.0), layer1 broadcast A-read

typedef __attribute__((ext_vector_type(8))) short bf16x8;
typedef __attribute__((ext_vector_type(4))) float f32x4;
typedef __attribute__((ext_vector_type(2))) unsigned int u32x2;
typedef __attribute__((ext_vector_type(4))) unsigned int u32x4;
typedef unsigned long long u64t;

#define HID 64

static __device__ __forceinline__ unsigned short f2bf(float f) {
    __hip_bfloat16 h = __float2bfloat16(f);
    return __builtin_bit_cast(unsigned short, h);
}
static __device__ __forceinline__ unsigned cvt_pk_bf16(float a, float b) {
    unsigned r;
    asm("v_cvt_pk_bf16_f32 %0, %1, %2" : "=v"(r) : "v"(a), "v"(b));
    return r;
}
static __device__ __forceinline__ void lds_fence() {
    asm volatile("s_waitcnt lgkmcnt(0)" ::: "memory");
}
#define MFMA16(a,b,c) __builtin_amdgcn_mfma_f32_16x16x32_bf16((a),(b),(c),0,0,0)

static __device__ __forceinline__ int lswz(int row, int col_shorts) {
    return row * 128 + ((col_shorts * 2) ^ ((row & 7) << 4));
}
static __device__ __forceinline__ f32x4 unpk(u64t q) {
    unsigned lo = (unsigned)q, hi = (unsigned)(q >> 32);
    f32x4 r;
    r[0] = __builtin_bit_cast(float, lo << 16);
    r[1] = __builtin_bit_cast(float, lo & 0xFFFF0000u);
    r[2] = __builtin_bit_cast(float, hi << 16);
    r[3] = __builtin_bit_cast(float, hi & 0xFFFF0000u);
    return r;
}

// fp32 emb (1M texels x 16B) -> bf16 table (1M x 8B)
__global__ __launch_bounds__(256) void conv_emb(const f32x4* __restrict__ emb,
                                                u32x2* __restrict__ tab) {
    int t = blockIdx.x * 256 + threadIdx.x;   // 4096 x 256 == 1M exactly
    f32x4 v = emb[t];
    u32x2 p = {cvt_pk_bf16(v[0], v[1]), cvt_pk_bf16(v[2], v[3])};
    tab[t] = p;
}

template<int BT>
__global__ __launch_bounds__(256, 4)
void dgn_fused(const float* __restrict__ x, const void* __restrict__ tabv,
               const float* __restrict__ w1, const float* __restrict__ b1,
               const float* __restrict__ w2, const float* __restrict__ b2,
               const float* __restrict__ w3, const float* __restrict__ b3,
               float* __restrict__ out, int n)
{
    __shared__ __align__(16) short lds_h[4][64][64];   // 32KB swizzled h1/h2 (+weight stage)
    __shared__ __align__(16) short lds_in[4][64][8];   //  4KB in8 / out staging

    const int tid = threadIdx.x, wid = tid >> 6, lane = tid & 63;
    const int cl = lane & 15, kg = lane >> 4, hb = cl * 4;
    char  *LhB = (char*)&lds_h[wid][0][0];
    short *Lin = &lds_in[wid][0][0];
    float *Lo  = (float*)Lin;

    // ---- stage weights block-wide into LDS, then build per-lane fragments ----
    float* Wst = (float*)&lds_h[0][0][0];
    {
        const f32x4* w2v = (const f32x4*)w2;
        f32x4* Wv = (f32x4*)Wst;
        #pragma unroll
        for (int i = 0; i < 4; ++i) Wv[tid + 256 * i] = w2v[tid + 256 * i];
        for (int idx = tid; idx < 320; idx += 256) Wst[4096 + idx] = w1[idx];
        if (tid < 64)  Wst[4416 + tid] = b1[tid];
        if (tid < 192) Wst[4480 + tid] = w3[tid];
        if (tid < 64)  Wst[4672 + tid] = b2[tid];
        if (tid < 3)   Wst[4736 + tid] = b3[tid];
    }
    __syncthreads();

    bf16x8 w1f[4];   // rows 0..4 = w1, row 5 = b1 (in8 slot5 carries 1.0)
    #pragma unroll
    for (int nt = 0; nt < 4; ++nt) {
        bf16x8 f = {};
        if (kg == 0) {
            #pragma unroll
            for (int j = 0; j < 5; ++j) f[j] = (short)f2bf(Wst[4096 + j * 64 + hb + nt]);
            f[5] = (short)f2bf(Wst[4416 + hb + nt]);
        }
        w1f[nt] = f;
    }
    bf16x8 w2f[2][4];
    #pragma unroll
    for (int ks = 0; ks < 2; ++ks) {
        f32x4 r[8];
        #pragma unroll
        for (int j = 0; j < 8; ++j)
            r[j] = *(const f32x4*)&Wst[(ks * 32 + kg * 8 + j) * 64 + hb];
        #pragma unroll
        for (int nt = 0; nt < 4; ++nt) {
            u32x4 w;
            #pragma unroll
            for (int jw = 0; jw < 4; ++jw)
                w[jw] = cvt_pk_bf16(r[2 * jw][nt], r[2 * jw + 1][nt]);
            w2f[ks][nt] = __builtin_bit_cast(bf16x8, w);
        }
    }
    bf16x8 w3f[2];
    #pragma unroll
    for (int ks = 0; ks < 2; ++ks) {
        bf16x8 f = {};
        if (cl < 3) {
            #pragma unroll
            for (int j = 0; j < 8; ++j)
                f[j] = (short)f2bf(Wst[4480 + (ks * 32 + kg * 8 + j) * 3 + cl]);
        }
        w3f[ks] = f;
    }
    float b2v[4];
    #pragma unroll
    for (int nt = 0; nt < 4; ++nt) b2v[nt] = Wst[4672 + hb + nt];
    const float b3v = (cl < 3) ? Wst[4736 + cl] : 0.f;
    __syncthreads();

    const u64t*  __restrict__ tab8 = (const u64t*)tabv;
    const f32x4* __restrict__ tabf = (const f32x4*)tabv;

    const int step = gridDim.x * 256;
    const int blk0 = blockIdx.x * 256;
    if (blk0 >= n) return;
    const int iters = (n - blk0 + step - 1) / step;
    const int wb0   = blk0 + wid * 64;

    #define LOADX(I, A, B, C) { int pt_ = wb0 + (I) * step + lane;               \
        int pc_ = pt_ < n ? pt_ : 0; const float* xp_ = x + 3 * pc_;             \
        A = __builtin_nontemporal_load(xp_);                                     \
        B = __builtin_nontemporal_load(xp_ + 1);                                 \
        C = __builtin_nontemporal_load(xp_ + 2); }

    #define GISSUE(U, V, Ta, Tb, Tc, Td, Fa, Fb, Fc, Fd, WX, WY) {               \
        float uf_ = (U) * 1024.f, vf_ = (V) * 1024.f;                            \
        int x0_ = (int)uf_; if (x0_ == 1024) x0_ = 0;                            \
        int x1_ = (x0_ + 1 == 1024) ? 1023 : x0_ + 1;                            \
        int y0_ = (int)vf_;                                                      \
        WX = uf_ - (float)x0_; WY = vf_ - (float)y0_;                            \
        if (y0_ > 1023) y0_ = 1023;                                              \
        int y1_ = (y0_ + 1 > 1023) ? 1023 : y0_ + 1;                             \
        int r0_ = y0_ << 10, r1_ = y1_ << 10;                                    \
        if (BT) { Ta = tab8[r0_ + x0_]; Tb = tab8[r0_ + x1_];                    \
                  Tc = tab8[r1_ + x0_]; Td = tab8[r1_ + x1_]; }                  \
        else    { Fa = tabf[r0_ + x0_]; Fb = tabf[r0_ + x1_];                    \
                  Fc = tabf[r1_ + x0_]; Fd = tabf[r1_ + x1_]; } }

    // ---------------- depth-2 pipeline ----------------
    u64t g00 = 0, g10 = 0, g01 = 0, g11 = 0;
    f32x4 e00 = {}, e10 = {}, e01 = {}, e11 = {};
    float cwx, cwy, cid;
    float nxi, nxu, nxv;
    {
        float pxi, pxu, pxv;
        LOADX(0, pxi, pxu, pxv);
        GISSUE(pxu, pxv, g00, g10, g01, g11, e00, e10, e01, e11, cwx, cwy);
        cid = pxi;
        LOADX(1, nxi, nxu, nxv);
    }

    for (int i = 0; i < iters; ++i) {
        u64t h00 = 0, h10 = 0, h01 = 0, h11 = 0;
        f32x4 f00 = {}, f10 = {}, f01 = {}, f11 = {};
        float hwx = 0.f, hwy = 0.f, hid = 0.f;
        const bool more = (i + 1 < iters);
        if (more) {
            GISSUE(nxu, nxv, h00, h10, h01, h11, f00, f10, f01, f11, hwx, hwy);
            hid = nxi;
            int nix = (i + 2 < iters) ? i + 2 : i + 1;
            LOADX(nix, nxi, nxu, nxv);
        }

        // ---- consume tile i: lerp, pack, LDS ----
        f32x4 v00, v10, v01, v11;
        if (BT) { v00 = unpk(g00); v10 = unpk(g10); v01 = unpk(g01); v11 = unpk(g11); }
        else    { v00 = e00; v10 = e10; v01 = e01; v11 = e11; }
        f32x4 vup = v00 + (v10 - v00) * cwx;
        f32x4 vdn = v01 + (v11 - v01) * cwx;
        f32x4 g   = vup + (vdn - vup) * cwy;

        u32x4 inq = {cvt_pk_bf16(cid, g[0]), cvt_pk_bf16(g[1], g[2]),
                     cvt_pk_bf16(g[3], 1.0f), 0u};     // slot5 = 1.0 (bias row)
        *(u32x4*)(Lin + lane * 8) = inq;
        lds_fence();

        // -------- layer 1: K=32 (rows 6..31 zero; kg>=1 annihilated by zero B) --------
        #pragma unroll
        for (int mt = 0; mt < 4; ++mt) {
            bf16x8 af = *(const bf16x8*)(Lin + (mt * 16 + cl) * 8);   // broadcast over kg
            f32x4 acc[4] = {};
            #pragma unroll
            for (int nt = 0; nt < 4; ++nt)
                acc[nt] = MFMA16(af, w1f[nt], acc[nt]);
            #pragma unroll
            for (int r = 0; r < 4; ++r) {
                int row = mt * 16 + kg * 4 + r;
                u32x2 p = {cvt_pk_bf16(fmaxf(acc[0][r], 0.f), fmaxf(acc[1][r], 0.f)),
                           cvt_pk_bf16(fmaxf(acc[2][r], 0.f), fmaxf(acc[3][r], 0.f))};
                *(u32x2*)(LhB + lswz(row, hb)) = p;
            }
        }
        lds_fence();

        // -------- layer 2: K=64 --------
        #pragma unroll
        for (int mt = 0; mt < 4; ++mt) {
            int arow = mt * 16 + cl;
            bf16x8 a0 = *(const bf16x8*)(LhB + lswz(arow, kg * 8));
            bf16x8 a1 = *(const bf16x8*)(LhB + lswz(arow, 32 + kg * 8));
            f32x4 acc[4];
            #pragma unroll
            for (int nt = 0; nt < 4; ++nt) {
                acc[nt] = (f32x4){b2v[nt], b2v[nt], b2v[nt], b2v[nt]};
                acc[nt] = MFMA16(a0, w2f[0][nt], acc[nt]);
                acc[nt] = MFMA16(a1, w2f[1][nt], acc[nt]);
            }
            #pragma unroll
            for (int r = 0; r < 4; ++r) {
                int row = mt * 16 + kg * 4 + r;
                u32x2 p = {cvt_pk_bf16(fmaxf(acc[0][r], 0.f), fmaxf(acc[1][r], 0.f)),
                           cvt_pk_bf16(fmaxf(acc[2][r], 0.f), fmaxf(acc[3][r], 0.f))};
                *(u32x2*)(LhB + lswz(row, hb)) = p;
            }
        }
        lds_fence();

        // -------- layer 3: K=64, 3 cols --------
        #pragma unroll
        for (int mt = 0; mt < 4; ++mt) {
            int arow = mt * 16 + cl;
            bf16x8 a0 = *(const bf16x8*)(LhB + lswz(arow, kg * 8));
            bf16x8 a1 = *(const bf16x8*)(LhB + lswz(arow, 32 + kg * 8));
            f32x4 acc = (f32x4){b3v, b3v, b3v, b3v};
            acc = MFMA16(a0, w3f[0], acc);
            acc = MFMA16(a1, w3f[1], acc);
            if (cl < 3) {
                #pragma unroll
                for (int r = 0; r < 4; ++r) {
                    float t = acc[r];
                    float s = __builtin_amdgcn_rcpf(1.0f + __expf(-t));
                    Lo[(mt * 16 + kg * 4 + r) * 3 + cl] = s;
                }
            }
        }
        lds_fence();

        const int wbase = wb0 + i * step;
        if (wbase + 64 <= n) {
            if (lane < 48)
                __builtin_nontemporal_store(*(const f32x4*)(Lo + lane * 4),
                                            (f32x4*)(out + wbase * 3 + lane * 4));
        } else {
            int pt = wbase + lane;
            if (pt < n) {
                out[pt * 3 + 0] = Lo[lane * 3 + 0];
                out[pt * 3 + 1] = Lo[lane * 3 + 1];
                out[pt * 3 + 2] = Lo[lane * 3 + 2];
            }
        }

        if (more) {
            g00 = h00; g10 = h10; g01 = h01; g11 = h11;
            e00 = f00; e10 = f10; e01 = f01; e11 = f11;
            cwx = hwx; cwy = hwy; cid = hid;
        }
    }
    #undef LOADX
    #undef GISSUE
}

extern "C" void kernel_launch(void* const* d_in, const int* in_sizes, int n_in,
                              void* d_out, int out_size, void* d_ws, size_t ws_size,
                              hipStream_t stream) {
    const float* x   = (const float*)d_in[0];
    const float* emb = (const float*)d_in[1];
    const float* w1  = (const float*)d_in[2];
    const float* b1  = (const float*)d_in[3];
    const float* w2  = (const float*)d_in[4];
    const float* b2  = (const float*)d_in[5];
    const float* w3  = (const float*)d_in[6];
    const float* b3  = (const float*)d_in[7];
    float* out = (float*)d_out;

    int n = in_sizes[0] / 3;
    int nblk = (n + 255) / 256;
    if (nblk > 2048) nblk = 2048;

    const size_t tab_bytes = (size_t)1024 * 1024 * 8;
    if (ws_size >= tab_bytes) {
        conv_emb<<<dim3(4096), dim3(256), 0, stream>>>((const f32x4*)emb, (u32x2*)d_ws);
        dgn_fused<1><<<dim3(nblk), dim3(256), 0, stream>>>(
            x, d_ws, w1, b1, w2, b2, w3, b3, out, n);
    } else {
        dgn_fused<0><<<dim3(nblk), dim3(256), 0, stream>>>(
            x, emb, w1, b1, w2, b2, w3, b3, out, n);
    }
}

// Round 6
// 127.570 us; speedup vs baseline: 1.3826x; 1.3826x over previous
//
#include <hip/hip_runtime.h>
#include <hip/hip_bf16.h>

// DenseGridNet R6: fused, (256,3) ONLY ((256,4) spills — R2/R5), bf16 table,
// pair-deep pipeline: 128 pts/wave/iter, 8 texel + 2 x loads in flight during MLP.

typedef __attribute__((ext_vector_type(8))) short bf16x8;
typedef __attribute__((ext_vector_type(4))) float f32x4;
typedef __attribute__((ext_vector_type(2))) unsigned int u32x2;
typedef __attribute__((ext_vector_type(4))) unsigned int u32x4;
typedef unsigned long long u64t;

#define HID 64

static __device__ __forceinline__ unsigned short f2bf(float f) {
    __hip_bfloat16 h = __float2bfloat16(f);
    return __builtin_bit_cast(unsigned short, h);
}
static __device__ __forceinline__ unsigned cvt_pk_bf16(float a, float b) {
    unsigned r;
    asm("v_cvt_pk_bf16_f32 %0, %1, %2" : "=v"(r) : "v"(a), "v"(b));
    return r;
}
static __device__ __forceinline__ void lds_fence() {
    asm volatile("s_waitcnt lgkmcnt(0)" ::: "memory");
}
#define MFMA16(a,b,c) __builtin_amdgcn_mfma_f32_16x16x32_bf16((a),(b),(c),0,0,0)

static __device__ __forceinline__ int lswz(int row, int col_shorts) {
    return row * 128 + ((col_shorts * 2) ^ ((row & 7) << 4));
}
static __device__ __forceinline__ f32x4 unpk(u64t q) {
    unsigned lo = (unsigned)q, hi = (unsigned)(q >> 32);
    f32x4 r;
    r[0] = __builtin_bit_cast(float, lo << 16);
    r[1] = __builtin_bit_cast(float, lo & 0xFFFF0000u);
    r[2] = __builtin_bit_cast(float, hi << 16);
    r[3] = __builtin_bit_cast(float, hi & 0xFFFF0000u);
    return r;
}

// fp32 emb (1M texels x 16B) -> bf16 table (1M x 8B)
__global__ __launch_bounds__(256) void conv_emb(const f32x4* __restrict__ emb,
                                                u32x2* __restrict__ tab) {
    int t = blockIdx.x * 256 + threadIdx.x;   // 4096 x 256 == 1M exactly
    f32x4 v = emb[t];
    u32x2 p = {cvt_pk_bf16(v[0], v[1]), cvt_pk_bf16(v[2], v[3])};
    tab[t] = p;
}

template<int BT>
__global__ __launch_bounds__(256, 3)
void dgn_fused(const float* __restrict__ x, const void* __restrict__ tabv,
               const float* __restrict__ w1, const float* __restrict__ b1,
               const float* __restrict__ w2, const float* __restrict__ b2,
               const float* __restrict__ w3, const float* __restrict__ b3,
               float* __restrict__ out, int n)
{
    __shared__ __align__(16) short lds_h[4][64][64];   // 32KB swizzled h1/h2 (+weight stage)
    __shared__ __align__(16) short lds_in[4][64][8];   //  4KB in8 / out staging

    const int tid = threadIdx.x, wid = tid >> 6, lane = tid & 63;
    const int cl = lane & 15, kg = lane >> 4, hb = cl * 4;
    char  *LhB = (char*)&lds_h[wid][0][0];
    short *Lin = &lds_in[wid][0][0];
    float *Lo  = (float*)Lin;

    // ---- stage weights block-wide into LDS, then build per-lane fragments ----
    float* Wst = (float*)&lds_h[0][0][0];
    {
        const f32x4* w2v = (const f32x4*)w2;
        f32x4* Wv = (f32x4*)Wst;
        #pragma unroll
        for (int i = 0; i < 4; ++i) Wv[tid + 256 * i] = w2v[tid + 256 * i];
        for (int idx = tid; idx < 320; idx += 256) Wst[4096 + idx] = w1[idx];
        if (tid < 64)  Wst[4416 + tid] = b1[tid];
        if (tid < 192) Wst[4480 + tid] = w3[tid];
        if (tid < 64)  Wst[4672 + tid] = b2[tid];
        if (tid < 3)   Wst[4736 + tid] = b3[tid];
    }
    __syncthreads();

    bf16x8 w1f[4];   // rows 0..4 = w1, row 5 = b1 (in8 slot5 carries 1.0); kg>=1 zero
    #pragma unroll
    for (int nt = 0; nt < 4; ++nt) {
        bf16x8 f = {};
        if (kg == 0) {
            #pragma unroll
            for (int j = 0; j < 5; ++j) f[j] = (short)f2bf(Wst[4096 + j * 64 + hb + nt]);
            f[5] = (short)f2bf(Wst[4416 + hb + nt]);
        }
        w1f[nt] = f;
    }
    bf16x8 w2f[2][4];
    #pragma unroll
    for (int ks = 0; ks < 2; ++ks) {
        f32x4 r[8];
        #pragma unroll
        for (int j = 0; j < 8; ++j)
            r[j] = *(const f32x4*)&Wst[(ks * 32 + kg * 8 + j) * 64 + hb];
        #pragma unroll
        for (int nt = 0; nt < 4; ++nt) {
            u32x4 w;
            #pragma unroll
            for (int jw = 0; jw < 4; ++jw)
                w[jw] = cvt_pk_bf16(r[2 * jw][nt], r[2 * jw + 1][nt]);
            w2f[ks][nt] = __builtin_bit_cast(bf16x8, w);
        }
    }
    bf16x8 w3f[2];
    #pragma unroll
    for (int ks = 0; ks < 2; ++ks) {
        bf16x8 f = {};
        if (cl < 3) {
            #pragma unroll
            for (int j = 0; j < 8; ++j)
                f[j] = (short)f2bf(Wst[4480 + (ks * 32 + kg * 8 + j) * 3 + cl]);
        }
        w3f[ks] = f;
    }
    float b2v[4];
    #pragma unroll
    for (int nt = 0; nt < 4; ++nt) b2v[nt] = Wst[4672 + hb + nt];
    const float b3v = (cl < 3) ? Wst[4736 + cl] : 0.f;
    __syncthreads();

    const u64t*  __restrict__ tab8 = (const u64t*)tabv;
    const f32x4* __restrict__ tabf = (const f32x4*)tabv;

    // pair geometry: block covers 512 pts/iter; wave covers 128 (tiles +0,+64)
    const int SP   = gridDim.x * 512;
    const int blk0 = blockIdx.x * 512;
    if (blk0 >= n) return;
    const int iters = (n - blk0 + SP - 1) / SP;
    const int wb0   = blk0 + wid * 128;

    #define LOADX(P, TO, A, B, C) { int pt_ = wb0 + (P) * SP + (TO) + lane;      \
        int pc_ = pt_ < n ? pt_ : 0; const float* xp_ = x + 3 * pc_;             \
        A = __builtin_nontemporal_load(xp_);                                     \
        B = __builtin_nontemporal_load(xp_ + 1);                                 \
        C = __builtin_nontemporal_load(xp_ + 2); }

    #define GISSUE(U, V, T, F, WX, WY) {                                         \
        float uf_ = (U) * 1024.f, vf_ = (V) * 1024.f;                            \
        int x0_ = (int)uf_; if (x0_ == 1024) x0_ = 0;                            \
        int x1_ = (x0_ + 1 == 1024) ? 1023 : x0_ + 1;                            \
        int y0_ = (int)vf_;                                                      \
        WX = uf_ - (float)x0_; WY = vf_ - (float)y0_;                            \
        if (y0_ > 1023) y0_ = 1023;                                              \
        int y1_ = (y0_ + 1 > 1023) ? 1023 : y0_ + 1;                             \
        int r0_ = y0_ << 10, r1_ = y1_ << 10;                                    \
        if (BT) { T[0] = tab8[r0_ + x0_]; T[1] = tab8[r0_ + x1_];                \
                  T[2] = tab8[r1_ + x0_]; T[3] = tab8[r1_ + x1_]; }              \
        else    { F[0] = tabf[r0_ + x0_]; F[1] = tabf[r0_ + x1_];                \
                  F[2] = tabf[r1_ + x0_]; F[3] = tabf[r1_ + x1_]; } }

    // full MLP for one 64-pt tile: lerp, pack, 3 layers, sigmoid, store
    #define MLP_TILE(T, F, WX, WY, CID, WBASE) {                                 \
        f32x4 v00_, v10_, v01_, v11_;                                            \
        if (BT) { v00_ = unpk(T[0]); v10_ = unpk(T[1]);                          \
                  v01_ = unpk(T[2]); v11_ = unpk(T[3]); }                        \
        else    { v00_ = F[0]; v10_ = F[1]; v01_ = F[2]; v11_ = F[3]; }          \
        f32x4 vup_ = v00_ + (v10_ - v00_) * (WX);                                \
        f32x4 vdn_ = v01_ + (v11_ - v01_) * (WX);                                \
        f32x4 g_   = vup_ + (vdn_ - vup_) * (WY);                                \
        u32x4 inq_ = {cvt_pk_bf16((CID), g_[0]), cvt_pk_bf16(g_[1], g_[2]),      \
                      cvt_pk_bf16(g_[3], 1.0f), 0u};                             \
        *(u32x4*)(Lin + lane * 8) = inq_;                                        \
        lds_fence();                                                             \
        _Pragma("unroll")                                                        \
        for (int mt = 0; mt < 4; ++mt) {                                         \
            bf16x8 af = {};                                                      \
            if (kg == 0) af = *(const bf16x8*)(Lin + (mt * 16 + cl) * 8);        \
            f32x4 acc[4] = {};                                                   \
            _Pragma("unroll")                                                    \
            for (int nt = 0; nt < 4; ++nt)                                       \
                acc[nt] = MFMA16(af, w1f[nt], acc[nt]);                          \
            _Pragma("unroll")                                                    \
            for (int r = 0; r < 4; ++r) {                                        \
                int row = mt * 16 + kg * 4 + r;                                  \
                u32x2 p = {cvt_pk_bf16(fmaxf(acc[0][r], 0.f), fmaxf(acc[1][r], 0.f)), \
                           cvt_pk_bf16(fmaxf(acc[2][r], 0.f), fmaxf(acc[3][r], 0.f))}; \
                *(u32x2*)(LhB + lswz(row, hb)) = p;                              \
            }                                                                    \
        }                                                                        \
        lds_fence();                                                             \
        _Pragma("unroll")                                                        \
        for (int mt = 0; mt < 4; ++mt) {                                         \
            int arow = mt * 16 + cl;                                             \
            bf16x8 a0 = *(const bf16x8*)(LhB + lswz(arow, kg * 8));              \
            bf16x8 a1 = *(const bf16x8*)(LhB + lswz(arow, 32 + kg * 8));         \
            f32x4 acc[4];                                                        \
            _Pragma("unroll")                                                    \
            for (int nt = 0; nt < 4; ++nt) {                                     \
                acc[nt] = (f32x4){b2v[nt], b2v[nt], b2v[nt], b2v[nt]};           \
                acc[nt] = MFMA16(a0, w2f[0][nt], acc[nt]);                       \
                acc[nt] = MFMA16(a1, w2f[1][nt], acc[nt]);                       \
            }                                                                    \
            _Pragma("unroll")                                                    \
            for (int r = 0; r < 4; ++r) {                                        \
                int row = mt * 16 + kg * 4 + r;                                  \
                u32x2 p = {cvt_pk_bf16(fmaxf(acc[0][r], 0.f), fmaxf(acc[1][r], 0.f)), \
                           cvt_pk_bf16(fmaxf(acc[2][r], 0.f), fmaxf(acc[3][r], 0.f))}; \
                *(u32x2*)(LhB + lswz(row, hb)) = p;                              \
            }                                                                    \
        }                                                                        \
        lds_fence();                                                             \
        _Pragma("unroll")                                                        \
        for (int mt = 0; mt < 4; ++mt) {                                         \
            int arow = mt * 16 + cl;                                             \
            bf16x8 a0 = *(const bf16x8*)(LhB + lswz(arow, kg * 8));              \
            bf16x8 a1 = *(const bf16x8*)(LhB + lswz(arow, 32 + kg * 8));         \
            f32x4 acc = (f32x4){b3v, b3v, b3v, b3v};                             \
            acc = MFMA16(a0, w3f[0], acc);                                       \
            acc = MFMA16(a1, w3f[1], acc);                                       \
            if (cl < 3) {                                                        \
                _Pragma("unroll")                                                \
                for (int r = 0; r < 4; ++r) {                                    \
                    float t = acc[r];                                            \
                    float s = __builtin_amdgcn_rcpf(1.0f + __expf(-t));          \
                    Lo[(mt * 16 + kg * 4 + r) * 3 + cl] = s;                     \
                }                                                                \
            }                                                                    \
        }                                                                        \
        lds_fence();                                                             \
        if ((WBASE) + 64 <= n) {                                                 \
            if (lane < 48)                                                       \
                __builtin_nontemporal_store(*(const f32x4*)(Lo + lane * 4),      \
                                            (f32x4*)(out + (WBASE) * 3 + lane * 4)); \
        } else {                                                                 \
            int pt_ = (WBASE) + lane;                                            \
            if (pt_ < n) {                                                       \
                out[pt_ * 3 + 0] = Lo[lane * 3 + 0];                             \
                out[pt_ * 3 + 1] = Lo[lane * 3 + 1];                             \
                out[pt_ * 3 + 2] = Lo[lane * 3 + 2];                             \
            }                                                                    \
        } }

    // ---------------- pair-deep pipeline ----------------
    u64t  cA[4] = {}, cB[4] = {};
    f32x4 eA[4] = {}, eB[4] = {};
    float cwxA, cwyA, cidA, cwxB, cwyB, cidB;
    float nxA0, nxA1, nxA2, nxB0, nxB1, nxB2;
    {
        float a0, a1, a2, q0, q1, q2;
        LOADX(0, 0,  a0, a1, a2);
        LOADX(0, 64, q0, q1, q2);
        GISSUE(a1, a2, cA, eA, cwxA, cwyA); cidA = a0;
        GISSUE(q1, q2, cB, eB, cwxB, cwyB); cidB = q0;
        LOADX(1, 0,  nxA0, nxA1, nxA2);
        LOADX(1, 64, nxB0, nxB1, nxB2);
    }

    for (int p = 0; p < iters; ++p) {
        u64t  tA[4] = {}, tB[4] = {};
        f32x4 fA[4] = {}, fB[4] = {};
        float twxA = 0.f, twyA = 0.f, tidA = 0.f;
        float twxB = 0.f, twyB = 0.f, tidB = 0.f;
        const bool more = (p + 1 < iters);
        if (more) {
            GISSUE(nxA1, nxA2, tA, fA, twxA, twyA); tidA = nxA0;
            GISSUE(nxB1, nxB2, tB, fB, twxB, twyB); tidB = nxB0;
            int np = (p + 2 < iters) ? p + 2 : p + 1;
            LOADX(np, 0,  nxA0, nxA1, nxA2);
            LOADX(np, 64, nxB0, nxB1, nxB2);
        }

        const int pb = wb0 + p * SP;
        MLP_TILE(cA, eA, cwxA, cwyA, cidA, pb)
        MLP_TILE(cB, eB, cwxB, cwyB, cidB, pb + 64)

        if (more) {
            #pragma unroll
            for (int j = 0; j < 4; ++j) { cA[j] = tA[j]; cB[j] = tB[j];
                                          eA[j] = fA[j]; eB[j] = fB[j]; }
            cwxA = twxA; cwyA = twyA; cidA = tidA;
            cwxB = twxB; cwyB = twyB; cidB = tidB;
        }
    }
    #undef LOADX
    #undef GISSUE
    #undef MLP_TILE
}

extern "C" void kernel_launch(void* const* d_in, const int* in_sizes, int n_in,
                              void* d_out, int out_size, void* d_ws, size_t ws_size,
                              hipStream_t stream) {
    const float* x   = (const float*)d_in[0];
    const float* emb = (const float*)d_in[1];
    const float* w1  = (const float*)d_in[2];
    const float* b1  = (const float*)d_in[3];
    const float* w2  = (const float*)d_in[4];
    const float* b2  = (const float*)d_in[5];
    const float* w3  = (const float*)d_in[6];
    const float* b3  = (const float*)d_in[7];
    float* out = (float*)d_out;

    int n = in_sizes[0] / 3;
    int nblk = (n + 511) / 512;
    if (nblk > 2048) nblk = 2048;

    const size_t tab_bytes = (size_t)1024 * 1024 * 8;
    if (ws_size >= tab_bytes) {
        conv_emb<<<dim3(4096), dim3(256), 0, stream>>>((const f32x4*)emb, (u32x2*)d_ws);
        dgn_fused<1><<<dim3(nblk), dim3(256), 0, stream>>>(
            x, d_ws, w1, b1, w2, b2, w3, b3, out, n);
    } else {
        dgn_fused<0><<<dim3(nblk), dim3(256), 0, stream>>>(
            x, emb, w1, b1, w2, b2, w3, b3, out, n);
    }
}

// Round 7
// 116.480 us; speedup vs baseline: 1.5143x; 1.0952x over previous
//
#include <hip/hip_runtime.h>
#include <hip/hip_bf16.h>

// DenseGridNet R7: clean two-pass.
//  conv_emb: fp32 emb -> bf16 table (8 MB) in d_ws[0..8MB)
//  gather2 : high-occupancy bilinear gather from bf16 table -> packed in8 (d_ws+8MB)
//  mlp2    : streaming MFMA MLP (1024 blocks resident, 8 tiles/wave, depth-2 prefetch)
//  Fallbacks: fp32-gather two-pass (ws>=n*16), fused fp32 (tiny ws).
//  NO nontemporal stores (R5/R6 write-amp), NO (256,4) on MFMA kernels (R2/R5 spill).

typedef __attribute__((ext_vector_type(8))) short bf16x8;
typedef __attribute__((ext_vector_type(4))) float f32x4;
typedef __attribute__((ext_vector_type(2))) unsigned int u32x2;
typedef __attribute__((ext_vector_type(4))) unsigned int u32x4;
typedef unsigned long long u64t;

#define HID 64

static __device__ __forceinline__ unsigned short f2bf(float f) {
    __hip_bfloat16 h = __float2bfloat16(f);
    return __builtin_bit_cast(unsigned short, h);
}
static __device__ __forceinline__ unsigned cvt_pk_bf16(float a, float b) {
    unsigned r;
    asm("v_cvt_pk_bf16_f32 %0, %1, %2" : "=v"(r) : "v"(a), "v"(b));
    return r;
}
static __device__ __forceinline__ void lds_fence() {
    asm volatile("s_waitcnt lgkmcnt(0)" ::: "memory");
}
#define MFMA16(a,b,c) __builtin_amdgcn_mfma_f32_16x16x32_bf16((a),(b),(c),0,0,0)

// byte offset into [64][64]-bf16 tile, XOR-swizzled (measured 0 conflicts)
static __device__ __forceinline__ int lswz(int row, int col_shorts) {
    return row * 128 + ((col_shorts * 2) ^ ((row & 7) << 4));
}
static __device__ __forceinline__ f32x4 unpk(u64t q) {
    unsigned lo = (unsigned)q, hi = (unsigned)(q >> 32);
    f32x4 r;
    r[0] = __builtin_bit_cast(float, lo << 16);
    r[1] = __builtin_bit_cast(float, lo & 0xFFFF0000u);
    r[2] = __builtin_bit_cast(float, hi << 16);
    r[3] = __builtin_bit_cast(float, hi & 0xFFFF0000u);
    return r;
}

// ================= weight fragments (shared by MFMA kernels) =================
struct Frags {
    bf16x8 w1f[4];      // L1 B-frags, col-permuted h=cl*4+nt; row5=b1 (in8 slot5=1.0)
    bf16x8 w2f[2][4];   // L2 B-frags (2 k-steps)
    bf16x8 w3f[2];      // L3 B-frags (3 cols, padded)
    float  b2v[4];
    float  b3v;
};

// Wst layout (floats): [0..4095]=w2, [4096..4415]=w1, [4416..4479]=b1,
//                      [4480..4671]=w3, [4672..4735]=b2, [4736..4738]=b3
static __device__ __forceinline__ void stage_and_build(
    float* Wst, int tid, int cl, int kg, int hb,
    const float* __restrict__ w1, const float* __restrict__ b1,
    const float* __restrict__ w2, const float* __restrict__ b2,
    const float* __restrict__ w3, const float* __restrict__ b3, Frags& F)
{
    {
        const f32x4* w2v = (const f32x4*)w2;
        f32x4* Wv = (f32x4*)Wst;
        #pragma unroll
        for (int i = 0; i < 4; ++i) Wv[tid + 256 * i] = w2v[tid + 256 * i];
        for (int idx = tid; idx < 320; idx += 256) Wst[4096 + idx] = w1[idx];
        if (tid < 64)  Wst[4416 + tid] = b1[tid];
        if (tid < 192) Wst[4480 + tid] = w3[tid];
        if (tid < 64)  Wst[4672 + tid] = b2[tid];
        if (tid < 3)   Wst[4736 + tid] = b3[tid];
    }
    __syncthreads();

    #pragma unroll
    for (int nt = 0; nt < 4; ++nt) {
        bf16x8 f = {};
        if (kg == 0) {
            #pragma unroll
            for (int j = 0; j < 5; ++j) f[j] = (short)f2bf(Wst[4096 + j * 64 + hb + nt]);
            f[5] = (short)f2bf(Wst[4416 + hb + nt]);
        }
        F.w1f[nt] = f;
    }
    #pragma unroll
    for (int ks = 0; ks < 2; ++ks) {
        f32x4 r[8];
        #pragma unroll
        for (int j = 0; j < 8; ++j)
            r[j] = *(const f32x4*)&Wst[(ks * 32 + kg * 8 + j) * 64 + hb];
        #pragma unroll
        for (int nt = 0; nt < 4; ++nt) {
            u32x4 w;
            #pragma unroll
            for (int jw = 0; jw < 4; ++jw)
                w[jw] = cvt_pk_bf16(r[2 * jw][nt], r[2 * jw + 1][nt]);
            F.w2f[ks][nt] = __builtin_bit_cast(bf16x8, w);
        }
    }
    #pragma unroll
    for (int ks = 0; ks < 2; ++ks) {
        bf16x8 f = {};
        if (cl < 3) {
            #pragma unroll
            for (int j = 0; j < 8; ++j)
                f[j] = (short)f2bf(Wst[4480 + (ks * 32 + kg * 8 + j) * 3 + cl]);
        }
        F.w3f[ks] = f;
    }
    #pragma unroll
    for (int nt = 0; nt < 4; ++nt) F.b2v[nt] = Wst[4672 + hb + nt];
    F.b3v = (cl < 3) ? Wst[4736 + cl] : 0.f;
    __syncthreads();
}

// ============ MLP for one 64-pt wave tile (inq pre-packed bf16 in8) ============
static __device__ __forceinline__ void mlp_tile(
    const Frags& F, char* LhB, short* Lin, float* Lo,
    int lane, int cl, int kg, int hb,
    u32x4 inq, float* __restrict__ out, int wbase, int n)
{
    *(u32x4*)(Lin + lane * 8) = inq;
    lds_fence();

    // L1: K=32 (rows 6..31 zero); kg>=1 frag rows are zero
    #pragma unroll
    for (int mt = 0; mt < 4; ++mt) {
        bf16x8 af = {};
        if (kg == 0) af = *(const bf16x8*)(Lin + (mt * 16 + cl) * 8);
        f32x4 acc[4] = {};
        #pragma unroll
        for (int nt = 0; nt < 4; ++nt) acc[nt] = MFMA16(af, F.w1f[nt], acc[nt]);
        #pragma unroll
        for (int r = 0; r < 4; ++r) {
            int row = mt * 16 + kg * 4 + r;
            u32x2 p = {cvt_pk_bf16(fmaxf(acc[0][r], 0.f), fmaxf(acc[1][r], 0.f)),
                       cvt_pk_bf16(fmaxf(acc[2][r], 0.f), fmaxf(acc[3][r], 0.f))};
            *(u32x2*)(LhB + lswz(row, hb)) = p;
        }
    }
    lds_fence();

    // L2: K=64
    #pragma unroll
    for (int mt = 0; mt < 4; ++mt) {
        int arow = mt * 16 + cl;
        bf16x8 a0 = *(const bf16x8*)(LhB + lswz(arow, kg * 8));
        bf16x8 a1 = *(const bf16x8*)(LhB + lswz(arow, 32 + kg * 8));
        f32x4 acc[4];
        #pragma unroll
        for (int nt = 0; nt < 4; ++nt) {
            acc[nt] = (f32x4){F.b2v[nt], F.b2v[nt], F.b2v[nt], F.b2v[nt]};
            acc[nt] = MFMA16(a0, F.w2f[0][nt], acc[nt]);
            acc[nt] = MFMA16(a1, F.w2f[1][nt], acc[nt]);
        }
        #pragma unroll
        for (int r = 0; r < 4; ++r) {
            int row = mt * 16 + kg * 4 + r;
            u32x2 p = {cvt_pk_bf16(fmaxf(acc[0][r], 0.f), fmaxf(acc[1][r], 0.f)),
                       cvt_pk_bf16(fmaxf(acc[2][r], 0.f), fmaxf(acc[3][r], 0.f))};
            *(u32x2*)(LhB + lswz(row, hb)) = p;
        }
    }
    lds_fence();

    // L3: K=64, 3 cols
    #pragma unroll
    for (int mt = 0; mt < 4; ++mt) {
        int arow = mt * 16 + cl;
        bf16x8 a0 = *(const bf16x8*)(LhB + lswz(arow, kg * 8));
        bf16x8 a1 = *(const bf16x8*)(LhB + lswz(arow, 32 + kg * 8));
        f32x4 acc = (f32x4){F.b3v, F.b3v, F.b3v, F.b3v};
        acc = MFMA16(a0, F.w3f[0], acc);
        acc = MFMA16(a1, F.w3f[1], acc);
        if (cl < 3) {
            #pragma unroll
            for (int r = 0; r < 4; ++r) {
                float t = acc[r];
                float s = __builtin_amdgcn_rcpf(1.0f + __expf(-t));
                Lo[(mt * 16 + kg * 4 + r) * 3 + cl] = s;
            }
        }
    }
    lds_fence();

    if (wbase + 64 <= n) {
        if (lane < 48)
            *(f32x4*)(out + wbase * 3 + lane * 4) = *(const f32x4*)(Lo + lane * 4);
    } else {
        int pt = wbase + lane;
        if (pt < n) {
            out[pt * 3 + 0] = Lo[lane * 3 + 0];
            out[pt * 3 + 1] = Lo[lane * 3 + 1];
            out[pt * 3 + 2] = Lo[lane * 3 + 2];
        }
    }
}

// ======================= pass 0: fp32 emb -> bf16 table =======================
__global__ __launch_bounds__(256) void conv_emb(const f32x4* __restrict__ emb,
                                                u32x2* __restrict__ tab) {
    int t = blockIdx.x * 256 + threadIdx.x;   // 4096 x 256 == 1M exactly
    f32x4 v = emb[t];
    u32x2 p = {cvt_pk_bf16(v[0], v[1]), cvt_pk_bf16(v[2], v[3])};
    tab[t] = p;
}

// ================= pass 1: bilinear gather -> packed bf16 in8 =================
template<int BT>   // BT=1: bf16 table, BT=0: fp32 emb
__global__ __launch_bounds__(256, 4)
void gather2(const float* __restrict__ x, const void* __restrict__ tv,
             u32x4* __restrict__ in8, int n)
{
    const u64t*  __restrict__ tab8 = (const u64t*)tv;
    const f32x4* __restrict__ tabf = (const f32x4*)tv;
    const int stride = gridDim.x * 256;
    for (int p0 = blockIdx.x * 256 + threadIdx.x; p0 < n; p0 += 2 * stride) {
        const int p1  = p0 + stride;
        const bool h1 = p1 < n;
        const int p1c = h1 ? p1 : p0;
        const float* xp0 = x + 3 * p0;
        const float* xp1 = x + 3 * p1c;
        float i0 = xp0[0], u0 = xp0[1], v0 = xp0[2];
        float i1 = xp1[0], u1 = xp1[1], v1 = xp1[2];

        float uf0 = u0 * 1024.f, vf0 = v0 * 1024.f;
        float uf1 = u1 * 1024.f, vf1 = v1 * 1024.f;
        int xa0 = (int)uf0; if (xa0 == 1024) xa0 = 0;
        int xb0 = (xa0 + 1 == 1024) ? 1023 : xa0 + 1;
        int ya0 = (int)vf0;
        float wx0 = uf0 - (float)xa0, wy0 = vf0 - (float)ya0;
        if (ya0 > 1023) ya0 = 1023;
        int yb0 = (ya0 + 1 > 1023) ? 1023 : ya0 + 1;
        int xa1 = (int)uf1; if (xa1 == 1024) xa1 = 0;
        int xb1 = (xa1 + 1 == 1024) ? 1023 : xa1 + 1;
        int ya1 = (int)vf1;
        float wx1 = uf1 - (float)xa1, wy1 = vf1 - (float)ya1;
        if (ya1 > 1023) ya1 = 1023;
        int yb1 = (ya1 + 1 > 1023) ? 1023 : ya1 + 1;

        f32x4 A0, B0, C0, D0, A1, B1, C1, D1;
        if (BT) {
            u64t qa0 = tab8[(ya0 << 10) + xa0];
            u64t qb0 = tab8[(ya0 << 10) + xb0];
            u64t qc0 = tab8[(yb0 << 10) + xa0];
            u64t qd0 = tab8[(yb0 << 10) + xb0];
            u64t qa1 = tab8[(ya1 << 10) + xa1];
            u64t qb1 = tab8[(ya1 << 10) + xb1];
            u64t qc1 = tab8[(yb1 << 10) + xa1];
            u64t qd1 = tab8[(yb1 << 10) + xb1];
            A0 = unpk(qa0); B0 = unpk(qb0); C0 = unpk(qc0); D0 = unpk(qd0);
            A1 = unpk(qa1); B1 = unpk(qb1); C1 = unpk(qc1); D1 = unpk(qd1);
        } else {
            A0 = tabf[(ya0 << 10) + xa0];
            B0 = tabf[(ya0 << 10) + xb0];
            C0 = tabf[(yb0 << 10) + xa0];
            D0 = tabf[(yb0 << 10) + xb0];
            A1 = tabf[(ya1 << 10) + xa1];
            B1 = tabf[(ya1 << 10) + xb1];
            C1 = tabf[(yb1 << 10) + xa1];
            D1 = tabf[(yb1 << 10) + xb1];
        }

        f32x4 up0 = A0 + (B0 - A0) * wx0;
        f32x4 dn0 = C0 + (D0 - C0) * wx0;
        f32x4 g0  = up0 + (dn0 - up0) * wy0;
        u32x4 o0 = {cvt_pk_bf16(i0, g0[0]), cvt_pk_bf16(g0[1], g0[2]),
                    cvt_pk_bf16(g0[3], 1.0f), 0u};    // slot5=1.0 (bias row)
        in8[p0] = o0;

        f32x4 up1 = A1 + (B1 - A1) * wx1;
        f32x4 dn1 = C1 + (D1 - C1) * wx1;
        f32x4 g1  = up1 + (dn1 - up1) * wy1;
        if (h1) {
            u32x4 o1 = {cvt_pk_bf16(i1, g1[0]), cvt_pk_bf16(g1[1], g1[2]),
                        cvt_pk_bf16(g1[3], 1.0f), 0u};
            in8[p1] = o1;
        }
    }
}

// ======================== pass 2: streaming MFMA MLP =========================
__global__ __launch_bounds__(256, 3)
void mlp2(const u32x4* __restrict__ in8,
          const float* __restrict__ w1, const float* __restrict__ b1,
          const float* __restrict__ w2, const float* __restrict__ b2,
          const float* __restrict__ w3, const float* __restrict__ b3,
          float* __restrict__ out, int n)
{
    __shared__ __align__(16) short lds_h[4][64][64];   // 32KB (weights stage + h1/h2)
    __shared__ __align__(16) short lds_in[4][64][8];   //  4KB in8 / out staging

    const int tid = threadIdx.x, wid = tid >> 6, lane = tid & 63;
    const int cl = lane & 15, kg = lane >> 4, hb = cl * 4;
    char  *LhB = (char*)&lds_h[wid][0][0];
    short *Lin = &lds_in[wid][0][0];
    float *Lo  = (float*)Lin;

    Frags F;
    stage_and_build((float*)&lds_h[0][0][0], tid, cl, kg, hb, w1, b1, w2, b2, w3, b3, F);

    const int tiles = (n + 63) >> 6;
    const int NW    = gridDim.x * 4;          // total waves
    const int gw    = blockIdx.x * 4 + wid;

    u32x4 q = {};
    if (gw < tiles) {
        int pt = gw * 64 + lane;
        q = in8[pt < n ? pt : (n - 1)];
    }
    for (int t = gw; t < tiles; t += NW) {
        int tn = t + NW;
        u32x4 qn = {};
        if (tn < tiles) {
            int pt = tn * 64 + lane;
            qn = in8[pt < n ? pt : (n - 1)];
        }
        mlp_tile(F, LhB, Lin, Lo, lane, cl, kg, hb, q, out, t * 64, n);
        q = qn;
    }
}

// ===================== fallback: fused fp32 (no workspace) =====================
__global__ __launch_bounds__(256, 3)
void fused_fp32(const float* __restrict__ x, const float* __restrict__ emb,
                const float* __restrict__ w1, const float* __restrict__ b1,
                const float* __restrict__ w2, const float* __restrict__ b2,
                const float* __restrict__ w3, const float* __restrict__ b3,
                float* __restrict__ out, int n)
{
    __shared__ __align__(16) short lds_h[4][64][64];
    __shared__ __align__(16) short lds_in[4][64][8];

    const int tid = threadIdx.x, wid = tid >> 6, lane = tid & 63;
    const int cl = lane & 15, kg = lane >> 4, hb = cl * 4;
    char  *LhB = (char*)&lds_h[wid][0][0];
    short *Lin = &lds_in[wid][0][0];
    float *Lo  = (float*)Lin;

    Frags F;
    stage_and_build((float*)&lds_h[0][0][0], tid, cl, kg, hb, w1, b1, w2, b2, w3, b3, F);

    const f32x4* __restrict__ emb4 = (const f32x4*)emb;
    for (int base = blockIdx.x * 256; base < n; base += gridDim.x * 256) {
        const int wbase = base + wid * 64;
        const int pt    = wbase + lane;
        float idf = 0.f, u = 0.f, vv = 0.f;
        if (pt < n) {
            const float* xp = x + 3 * pt;
            idf = xp[0]; u = xp[1]; vv = xp[2];
        }
        float uf = u * 1024.f, vf = vv * 1024.f;
        int x0 = (int)uf; if (x0 == 1024) x0 = 0;
        int x1i = (x0 + 1 == 1024) ? 1023 : x0 + 1;
        int y0 = (int)vf;
        float wx = uf - (float)x0, wy = vf - (float)y0;
        if (y0 > 1023) y0 = 1023;
        int y1 = (y0 + 1 > 1023) ? 1023 : y0 + 1;

        f32x4 v00 = emb4[(y0 << 10) + x0];
        f32x4 v10 = emb4[(y0 << 10) + x1i];
        f32x4 v01 = emb4[(y1 << 10) + x0];
        f32x4 v11 = emb4[(y1 << 10) + x1i];
        f32x4 vup = v00 + (v10 - v00) * wx;
        f32x4 vdn = v01 + (v11 - v01) * wx;
        f32x4 g   = vup + (vdn - vup) * wy;

        u32x4 inq = {cvt_pk_bf16(idf, g[0]), cvt_pk_bf16(g[1], g[2]),
                     cvt_pk_bf16(g[3], 1.0f), 0u};
        mlp_tile(F, LhB, Lin, Lo, lane, cl, kg, hb, inq, out, wbase, n);
    }
}

extern "C" void kernel_launch(void* const* d_in, const int* in_sizes, int n_in,
                              void* d_out, int out_size, void* d_ws, size_t ws_size,
                              hipStream_t stream) {
    const float* x   = (const float*)d_in[0];
    const float* emb = (const float*)d_in[1];
    const float* w1  = (const float*)d_in[2];
    const float* b1  = (const float*)d_in[3];
    const float* w2  = (const float*)d_in[4];
    const float* b2  = (const float*)d_in[5];
    const float* w3  = (const float*)d_in[6];
    const float* b3  = (const float*)d_in[7];
    float* out = (float*)d_out;

    int n = in_sizes[0] / 3;
    const size_t tab_bytes = (size_t)8 * 1024 * 1024;
    const size_t in8_bytes = (size_t)n * 16;

    int nthrG = (n + 1) / 2;
    int nblkG = (nthrG + 255) / 256; if (nblkG > 4096) nblkG = 4096;
    int nblkM = 1024;                 // exactly resident (4 blocks/CU x 256 CU)
    int tiles = (n + 63) / 64;
    if (nblkM * 4 > tiles) nblkM = (tiles + 3) / 4;   // small-n safety
    if (nblkM < 1) nblkM = 1;

    if (ws_size >= tab_bytes + in8_bytes) {
        u32x4* in8 = (u32x4*)((char*)d_ws + tab_bytes);
        conv_emb<<<dim3(4096), dim3(256), 0, stream>>>((const f32x4*)emb, (u32x2*)d_ws);
        gather2<1><<<dim3(nblkG), dim3(256), 0, stream>>>(x, d_ws, in8, n);
        mlp2<<<dim3(nblkM), dim3(256), 0, stream>>>(in8, w1, b1, w2, b2, w3, b3, out, n);
    } else if (ws_size >= in8_bytes) {
        u32x4* in8 = (u32x4*)d_ws;
        gather2<0><<<dim3(nblkG), dim3(256), 0, stream>>>(x, emb, in8, n);
        mlp2<<<dim3(nblkM), dim3(256), 0, stream>>>(in8, w1, b1, w2, b2, w3, b3, out, n);
    } else {
        int nblk = (n + 255) / 256; if (nblk > 2048) nblk = 2048;
        fused_fp32<<<dim3(nblk), dim3(256), 0, stream>>>(
            x, emb, w1, b1, w2, b2, w3, b3, out, n);
    }
}